// Round 4
// baseline (445.499 us; speedup 1.0000x reference)
//
#include <hip/hip_runtime.h>

// out = noised + (2*STD) * noise, STD = 0.05  ->  out = a + 0.1f * b
// N = 64*3*512*512 = 50,331,648 fp32 elements (divisible by 4).
// Pure memory-bound elementwise: float4 grid-stride loop.

__global__ __launch_bounds__(256) void gaussian_noise_add_kernel(
    const float4* __restrict__ a,
    const float4* __restrict__ b,
    float4* __restrict__ out,
    int n4)
{
    int stride = gridDim.x * blockDim.x;
    for (int i = blockIdx.x * blockDim.x + threadIdx.x; i < n4; i += stride) {
        float4 va = a[i];
        float4 vb = b[i];
        float4 vo;
        vo.x = fmaf(0.1f, vb.x, va.x);
        vo.y = fmaf(0.1f, vb.y, va.y);
        vo.z = fmaf(0.1f, vb.z, va.z);
        vo.w = fmaf(0.1f, vb.w, va.w);
        out[i] = vo;
    }
}

// Scalar tail kernel (defensive; n is divisible by 4 for this problem).
__global__ void gaussian_noise_tail_kernel(
    const float* __restrict__ a,
    const float* __restrict__ b,
    float* __restrict__ out,
    int start, int n)
{
    int i = start + blockIdx.x * blockDim.x + threadIdx.x;
    if (i < n) out[i] = fmaf(0.1f, b[i], a[i]);
}

extern "C" void kernel_launch(void* const* d_in, const int* in_sizes, int n_in,
                              void* d_out, int out_size, void* d_ws, size_t ws_size,
                              hipStream_t stream)
{
    const float* a = (const float*)d_in[0];   // noised
    const float* b = (const float*)d_in[1];   // noise
    float* out = (float*)d_out;
    int n = out_size;
    int n4 = n / 4;

    const int block = 256;
    // Memory-bound: cap grid at ~2048 blocks (256 CUs x 8 blocks), grid-stride the rest.
    int grid = (n4 + block - 1) / block;
    if (grid > 2048) grid = 2048;
    if (grid > 0) {
        gaussian_noise_add_kernel<<<grid, block, 0, stream>>>(
            (const float4*)a, (const float4*)b, (float4*)out, n4);
    }

    int tail_start = n4 * 4;
    int tail = n - tail_start;
    if (tail > 0) {
        gaussian_noise_tail_kernel<<<(tail + block - 1) / block, block, 0, stream>>>(
            a, b, out, tail_start, n);
    }
}